// Round 2
// baseline (429.959 us; speedup 1.0000x reference)
//
#include <hip/hip_runtime.h>
#include <stdint.h>

// Problem constants
#define N_ATOM 2048
#define K_TOT  32768        // N_ATOM * 16  (k = b*16 + f)
#define KCH    2048         // k per block (16 K-chunks)
#define BK2    128          // k per pipeline iteration
#define NIT    (KCH / BK2)  // 16

typedef __attribute__((ext_vector_type(8))) short bf16x8;
typedef __attribute__((ext_vector_type(4))) float f32x4;

typedef __attribute__((address_space(3))) uint32_t lds_u32;
typedef __attribute__((address_space(1))) uint32_t gbl_u32;

__device__ __forceinline__ void async_ld16(const void* g, void* l) {
  __builtin_amdgcn_global_load_lds((const gbl_u32*)g, (lds_u32*)l, 16, 0, 0);
}

// f32 -> bf16 round-to-nearest-even
__device__ __forceinline__ unsigned short f2bf(float x) {
  union { float f; uint32_t u; } v; v.f = x;
  uint32_t r = v.u + 0x7FFFu + ((v.u >> 16) & 1u);
  return (unsigned short)(r >> 16);
}

// ---------------------------------------------------------------------------
// Kernel 1: G[b][o][f] = sum_d node[b,d] * filters[o,f,d]   (bf16 output)
// GEMM: C[m=b][n=o*16+f] = node(2048x128) @ filters_rows(n,:128)^T
// C row-major (row stride 2048) IS the [b][o][f] layout.
// ---------------------------------------------------------------------------
__global__ __launch_bounds__(256) void k_gt(const float* __restrict__ node,
                                            const float* __restrict__ filt,
                                            unsigned short* __restrict__ Gt) {
  __shared__ unsigned short As[128 * 136];  // [m][k] bf16
  __shared__ unsigned short Bs[128 * 136];  // [n][k] bf16
  const int t  = threadIdx.x;
  const int b0 = blockIdx.x * 128;
  const int n0 = blockIdx.y * 128;

#pragma unroll
  for (int rep = 0; rep < 16; ++rep) {
    int q = rep * 256 + t;
    int row = q >> 5, c4 = q & 31;
    float4 v = *(const float4*)(node + (size_t)(b0 + row) * 128 + c4 * 4);
    unsigned short* dst = &As[row * 136 + c4 * 4];
    dst[0] = f2bf(v.x); dst[1] = f2bf(v.y); dst[2] = f2bf(v.z); dst[3] = f2bf(v.w);
  }
#pragma unroll
  for (int rep = 0; rep < 32; ++rep) {
    int q = rep * 256 + t;
    int row = q >> 6, c2 = q & 63;
    float2 v = *(const float2*)(filt + (size_t)(n0 + row) * 130 + c2 * 2);
    unsigned short* dst = &Bs[row * 136 + c2 * 2];
    dst[0] = f2bf(v.x); dst[1] = f2bf(v.y);
  }
  __syncthreads();

  const int w = t >> 6, l = t & 63;
  const int lm = l & 15, q4 = l >> 4;

  f32x4 acc[2][8];
#pragma unroll
  for (int ms = 0; ms < 2; ++ms)
#pragma unroll
    for (int ns = 0; ns < 8; ++ns)
      acc[ms][ns] = (f32x4){0.f, 0.f, 0.f, 0.f};

#pragma unroll
  for (int ks = 0; ks < 4; ++ks) {
    int ko = ks * 32 + q4 * 8;
    bf16x8 a[2], b[8];
#pragma unroll
    for (int ms = 0; ms < 2; ++ms) {
      int m = w * 32 + ms * 16 + lm;
      a[ms] = *(const bf16x8*)&As[m * 136 + ko];
    }
#pragma unroll
    for (int ns = 0; ns < 8; ++ns) {
      int n = ns * 16 + lm;
      b[ns] = *(const bf16x8*)&Bs[n * 136 + ko];
    }
#pragma unroll
    for (int ms = 0; ms < 2; ++ms)
#pragma unroll
      for (int ns = 0; ns < 8; ++ns)
        acc[ms][ns] = __builtin_amdgcn_mfma_f32_16x16x32_bf16(a[ms], b[ns], acc[ms][ns], 0, 0, 0);
  }

#pragma unroll
  for (int ms = 0; ms < 2; ++ms)
#pragma unroll
    for (int ns = 0; ns < 8; ++ns)
#pragma unroll
      for (int i = 0; i < 4; ++i) {
        int m = w * 32 + ms * 16 + q4 * 4 + i;
        int n = ns * 16 + lm;
        Gt[(size_t)(b0 + m) * 2048 + n0 + n] = f2bf(acc[ms][ns][i]);
      }
}

// ---------------------------------------------------------------------------
// Kernel 2: out[a][o] = sum_{f,j} bond[a,f,j] * filters[o,f,128+j]
// 16 atoms/block; filter bond-slice staged in LDS once (kills the stride-520B
// global re-reads of the old version). Also initializes d_out.
// ---------------------------------------------------------------------------
__global__ __launch_bounds__(256) void k_bond(const float* __restrict__ bond,
                                              const float* __restrict__ filt,
                                              float* __restrict__ out) {
  __shared__ float fb[128 * 32];  // [o][f*2+j], 16 KB
  __shared__ float bl[16 * 32];   // [a_rel][f*2+j], 2 KB
  const int t  = threadIdx.x;
  const int a0 = blockIdx.x * 16;

#pragma unroll
  for (int r = 0; r < 16; ++r) {
    int idx = r * 256 + t;          // 4096 = 128 o * 32
    int o = idx >> 5, fj = idx & 31;
    int f = fj >> 1, j = fj & 1;
    fb[idx] = filt[(size_t)o * 2080 + f * 130 + 128 + j];
  }
  bl[t]       = bond[(size_t)a0 * 32 + t];
  bl[256 + t] = bond[(size_t)a0 * 32 + 256 + t];
  __syncthreads();

#pragma unroll
  for (int r = 0; r < 8; ++r) {
    int idx = r * 256 + t;          // 2048 = 16 a * 128 o
    int aa = idx >> 7, o = idx & 127;
    const float2* bp = (const float2*)&bl[aa * 32];
    const float2* fp = (const float2*)&fb[o * 32];
    float acc = 0.f;
#pragma unroll
    for (int f = 0; f < 16; ++f) {
      float2 b2 = bp[f], f2 = fp[f];
      acc += b2.x * f2.x + b2.y * f2.y;
    }
    out[(size_t)(a0 + aa) * 128 + o] = acc;
  }
}

// ---------------------------------------------------------------------------
// Kernel 3: out[a][o] += conn2d(2048 x 32768) @ G(32768 x 128), split-K=16.
// A: direct global->VGPR fragment loads (no LDS). Wave pattern per load pair
//    = 16 full 128B lines; per row per iter = 512 B contiguous, streamed
//    sequentially to 8 KB/row over the block -> DRAM row-buffer friendly.
// B: Gt[b][o][f] bf16, double-buffered LDS via global_load_lds (contiguous).
// Pipeline: one barrier/iter; next-iter A-reg loads + B-async issued BEFORE
// compute so the barrier's vmcnt(0) drain overlaps the compute phase.
// ---------------------------------------------------------------------------
__global__ __launch_bounds__(256, 1) void k_main(const float* __restrict__ conn,
                                                 const unsigned short* __restrict__ Gt,
                                                 float* __restrict__ out) {
  __shared__ unsigned short Bh[2][8 * 128 * 16];  // 2 x 32 KB, [b_rel][o][f]

  const int t  = threadIdx.x;
  const int w  = t >> 6, l = t & 63;
  const int lm = l & 15, q4 = l >> 4;
  const int a0 = blockIdx.x * 128;
  const int kc = blockIdx.y * KCH;

  f32x4 acc[2][8];
#pragma unroll
  for (int ms = 0; ms < 2; ++ms)
#pragma unroll
    for (int ns = 0; ns < 8; ++ns)
      acc[ms][ns] = (f32x4){0.f, 0.f, 0.f, 0.f};

  // per-lane A row bases (rows this lane's fragments live on)
  const float* arow0 = conn + (size_t)(a0 + w * 32 + lm) * K_TOT;       // ms=0
  const float* arow1 = conn + (size_t)(a0 + w * 32 + 16 + lm) * K_TOT;  // ms=1

  // ---- B async stage: 32 KB contiguous from Gt + k0*128 shorts ----
  auto stageB = [&](int buf, int k0) {
    const char* gB = (const char*)(Gt + (size_t)k0 * 128);
#pragma unroll
    for (int r = 0; r < 8; ++r) {
      const void* g = gB + (size_t)(r * 256 + t) * 16;
      void* lb = (void*)((char*)&Bh[buf][0] + r * 4096 + w * 1024);  // wave-uniform
      async_ld16(g, lb);
    }
  };

  // ---- A register loads: [ms][kk][lo/hi] fp32 ----
  float4 Ar[2][4][2];
  auto loadA = [&](int k0) {
#pragma unroll
    for (int kk = 0; kk < 4; ++kk) {
      int off = k0 + kk * 32 + q4 * 8;
      Ar[0][kk][0] = *(const float4*)(arow0 + off);
      Ar[0][kk][1] = *(const float4*)(arow0 + off + 4);
      Ar[1][kk][0] = *(const float4*)(arow1 + off);
      Ar[1][kk][1] = *(const float4*)(arow1 + off + 4);
    }
  };

  // prologue
  stageB(0, kc);
  loadA(kc);
  __syncthreads();  // drain: Bh[0] + Ar(it=0) ready

  for (int it = 0; it < NIT; ++it) {
    const int cur = it & 1;

    // convert current A to bf16 fragments (frees Ar for the next loads)
    bf16x8 af[2][4];
#pragma unroll
    for (int ms = 0; ms < 2; ++ms)
#pragma unroll
      for (int kk = 0; kk < 4; ++kk) {
        float4 lo = Ar[ms][kk][0], hi = Ar[ms][kk][1];
        bf16x8 av;
        av[0] = (short)f2bf(lo.x); av[1] = (short)f2bf(lo.y);
        av[2] = (short)f2bf(lo.z); av[3] = (short)f2bf(lo.w);
        av[4] = (short)f2bf(hi.x); av[5] = (short)f2bf(hi.y);
        av[6] = (short)f2bf(hi.z); av[7] = (short)f2bf(hi.w);
        af[ms][kk] = av;
      }

    // issue next iteration's loads BEFORE compute (overlap + barrier drain)
    if (it + 1 < NIT) {
      stageB(1 - cur, kc + (it + 1) * BK2);
      loadA(kc + (it + 1) * BK2);
    }

    // compute: 4 K-steps of 16x16x32 over Bh[cur]
#pragma unroll
    for (int kk = 0; kk < 4; ++kk) {
      const int b_rel = 2 * kk + (q4 >> 1);
      const int f0 = (q4 & 1) * 8;
      bf16x8 b[8];
#pragma unroll
      for (int ns = 0; ns < 8; ++ns) {
        int o = ns * 16 + lm;
        b[ns] = *(const bf16x8*)&Bh[cur][b_rel * 2048 + o * 16 + f0];
      }
#pragma unroll
      for (int ms = 0; ms < 2; ++ms)
#pragma unroll
        for (int ns = 0; ns < 8; ++ns)
          acc[ms][ns] = __builtin_amdgcn_mfma_f32_16x16x32_bf16(af[ms][kk], b[ns], acc[ms][ns], 0, 0, 0);
    }

    __syncthreads();  // drains next-iter loads (overlapped) + protects Bh swap
  }

  // epilogue: split-K combine via fp32 atomics
#pragma unroll
  for (int ms = 0; ms < 2; ++ms)
#pragma unroll
    for (int ns = 0; ns < 8; ++ns)
#pragma unroll
      for (int i = 0; i < 4; ++i) {
        int m = w * 32 + ms * 16 + q4 * 4 + i;
        int n = ns * 16 + lm;
        atomicAdd(&out[(size_t)(a0 + m) * 128 + n], acc[ms][ns][i]);
      }
}

// ---------------------------------------------------------------------------
extern "C" void kernel_launch(void* const* d_in, const int* in_sizes, int n_in,
                              void* d_out, int out_size, void* d_ws, size_t ws_size,
                              hipStream_t stream) {
  const float* node = (const float*)d_in[0];  // (2048, 128)
  const float* conn = (const float*)d_in[1];  // (2048, 2048, 16)
  const float* bond = (const float*)d_in[2];  // (2048, 16, 2)
  const float* filt = (const float*)d_in[3];  // (128, 16, 130)
  float* out = (float*)d_out;                 // (2048, 128)

  if (ws_size < (size_t)N_ATOM * 2048 * sizeof(unsigned short)) return;  // need 8 MB
  unsigned short* Gt = (unsigned short*)d_ws;  // [b][o][f] bf16, 8 MB

  k_gt  <<<dim3(16, 16), 256, 0, stream>>>(node, filt, Gt);
  k_bond<<<dim3(128),    256, 0, stream>>>(bond, filt, out);
  k_main<<<dim3(16, 16), 256, 0, stream>>>(conn, Gt, out);
}

// Round 4
// 417.139 us; speedup vs baseline: 1.0307x; 1.0307x over previous
//
#include <hip/hip_runtime.h>
#include <stdint.h>

// Problem constants
#define N_ATOM 2048
#define K_TOT  32768        // N_ATOM * 16  (k = b*16 + f)
#define KCH    2048         // k per block (16 K-chunks)
#define BK2    128          // k per pipeline iteration
#define NIT    (KCH / BK2)  // 16

typedef __attribute__((ext_vector_type(8))) short bf16x8;
typedef __attribute__((ext_vector_type(4))) float f32x4;

typedef __attribute__((address_space(3))) uint32_t lds_u32;
typedef __attribute__((address_space(1))) uint32_t gbl_u32;

__device__ __forceinline__ void async_ld16(const void* g, void* l) {
  __builtin_amdgcn_global_load_lds((const gbl_u32*)g, (lds_u32*)l, 16, 0, 0);
}

// f32 -> bf16 round-to-nearest-even (used in k_gt/k_bond staging)
__device__ __forceinline__ unsigned short f2bf(float x) {
  union { float f; uint32_t u; } v; v.f = x;
  uint32_t r = v.u + 0x7FFFu + ((v.u >> 16) & 1u);
  return (unsigned short)(r >> 16);
}

// pack two f32 -> bf16x2 (round-to-nearest, ties-down): 2 v_add + 1 v_perm
__device__ __forceinline__ uint32_t pack_bf2(float x, float y) {
  union { float f; uint32_t u; } a, b;
  a.f = x; b.f = y;
  uint32_t au = a.u + 0x7FFFu;
  uint32_t bu = b.u + 0x7FFFu;
  // bytes: result = [bu.b3 bu.b2 au.b3 au.b2] -> low16 = x_hi, high16 = y_hi
  return __builtin_amdgcn_perm(bu, au, 0x07060302u);
}

// ---------------------------------------------------------------------------
// Kernel 1: G[b][o][f] = sum_d node[b,d] * filters[o,f,d]   (bf16 output)
// GEMM: C[m=b][n=o*16+f] = node(2048x128) @ filters_rows(n,:128)^T
// C row-major (row stride 2048) IS the [b][o][f] layout.
// ---------------------------------------------------------------------------
__global__ __launch_bounds__(256) void k_gt(const float* __restrict__ node,
                                            const float* __restrict__ filt,
                                            unsigned short* __restrict__ Gt) {
  __shared__ unsigned short As[128 * 136];  // [m][k] bf16
  __shared__ unsigned short Bs[128 * 136];  // [n][k] bf16
  const int t  = threadIdx.x;
  const int b0 = blockIdx.x * 128;
  const int n0 = blockIdx.y * 128;

#pragma unroll
  for (int rep = 0; rep < 16; ++rep) {
    int q = rep * 256 + t;
    int row = q >> 5, c4 = q & 31;
    float4 v = *(const float4*)(node + (size_t)(b0 + row) * 128 + c4 * 4);
    unsigned short* dst = &As[row * 136 + c4 * 4];
    dst[0] = f2bf(v.x); dst[1] = f2bf(v.y); dst[2] = f2bf(v.z); dst[3] = f2bf(v.w);
  }
#pragma unroll
  for (int rep = 0; rep < 32; ++rep) {
    int q = rep * 256 + t;
    int row = q >> 6, c2 = q & 63;
    float2 v = *(const float2*)(filt + (size_t)(n0 + row) * 130 + c2 * 2);
    unsigned short* dst = &Bs[row * 136 + c2 * 2];
    dst[0] = f2bf(v.x); dst[1] = f2bf(v.y);
  }
  __syncthreads();

  const int w = t >> 6, l = t & 63;
  const int lm = l & 15, q4 = l >> 4;

  f32x4 acc[2][8];
#pragma unroll
  for (int ms = 0; ms < 2; ++ms)
#pragma unroll
    for (int ns = 0; ns < 8; ++ns)
      acc[ms][ns] = (f32x4){0.f, 0.f, 0.f, 0.f};

#pragma unroll
  for (int ks = 0; ks < 4; ++ks) {
    int ko = ks * 32 + q4 * 8;
    bf16x8 a[2], b[8];
#pragma unroll
    for (int ms = 0; ms < 2; ++ms) {
      int m = w * 32 + ms * 16 + lm;
      a[ms] = *(const bf16x8*)&As[m * 136 + ko];
    }
#pragma unroll
    for (int ns = 0; ns < 8; ++ns) {
      int n = ns * 16 + lm;
      b[ns] = *(const bf16x8*)&Bs[n * 136 + ko];
    }
#pragma unroll
    for (int ms = 0; ms < 2; ++ms)
#pragma unroll
      for (int ns = 0; ns < 8; ++ns)
        acc[ms][ns] = __builtin_amdgcn_mfma_f32_16x16x32_bf16(a[ms], b[ns], acc[ms][ns], 0, 0, 0);
  }

#pragma unroll
  for (int ms = 0; ms < 2; ++ms)
#pragma unroll
    for (int ns = 0; ns < 8; ++ns)
#pragma unroll
      for (int i = 0; i < 4; ++i) {
        int m = w * 32 + ms * 16 + q4 * 4 + i;
        int n = ns * 16 + lm;
        Gt[(size_t)(b0 + m) * 2048 + n0 + n] = f2bf(acc[ms][ns][i]);
      }
}

// ---------------------------------------------------------------------------
// Kernel 2: out[a][o] = sum_{f,j} bond[a,f,j] * filters[o,f,128+j]
// 16 atoms/block; filter bond-slice staged in LDS. Initializes d_out.
// ---------------------------------------------------------------------------
__global__ __launch_bounds__(256) void k_bond(const float* __restrict__ bond,
                                              const float* __restrict__ filt,
                                              float* __restrict__ out) {
  __shared__ float fb[128 * 32];  // [o][f*2+j], 16 KB
  __shared__ float bl[16 * 32];   // [a_rel][f*2+j], 2 KB
  const int t  = threadIdx.x;
  const int a0 = blockIdx.x * 16;

#pragma unroll
  for (int r = 0; r < 16; ++r) {
    int idx = r * 256 + t;          // 4096 = 128 o * 32
    int o = idx >> 5, fj = idx & 31;
    int f = fj >> 1, j = fj & 1;
    fb[idx] = filt[(size_t)o * 2080 + f * 130 + 128 + j];
  }
  bl[t]       = bond[(size_t)a0 * 32 + t];
  bl[256 + t] = bond[(size_t)a0 * 32 + 256 + t];
  __syncthreads();

#pragma unroll
  for (int r = 0; r < 8; ++r) {
    int idx = r * 256 + t;          // 2048 = 16 a * 128 o
    int aa = idx >> 7, o = idx & 127;
    const float2* bp = (const float2*)&bl[aa * 32];
    const float2* fp = (const float2*)&fb[o * 32];
    float acc = 0.f;
#pragma unroll
    for (int f = 0; f < 16; ++f) {
      float2 b2 = bp[f], f2 = fp[f];
      acc += b2.x * f2.x + b2.y * f2.y;
    }
    out[(size_t)(a0 + aa) * 128 + o] = acc;
  }
}

// ---------------------------------------------------------------------------
// Kernel 3: out[a][o] += conn2d(2048 x 32768) @ G(32768 x 128), split-K=16.
// 512 threads / 8 waves per block, wave owns 16 rows x 128 cols:
//   per-wave VGPR ~130 -> 2 waves/SIMD co-resident (latency hiding across
//   the per-iteration barrier; R2's 1 wave/SIMD exposed every stall).
// A: non-temporal global->VGPR fragment loads (stream-once, keep L2 for Gt).
// B: Gt[b][o][f] bf16, double-buffered LDS via global_load_lds.
// One barrier/iter; next-iter loads issued BEFORE compute.
// ---------------------------------------------------------------------------
__global__ __launch_bounds__(512, 2) void k_main(const float* __restrict__ conn,
                                                 const unsigned short* __restrict__ Gt,
                                                 float* __restrict__ out) {
  __shared__ unsigned short Bh[2][8 * 128 * 16];  // 2 x 32 KB, [b_rel][o][f]

  const int t  = threadIdx.x;
  const int w  = t >> 6, l = t & 63;
  const int lm = l & 15, q4 = l >> 4;
  const int a0 = blockIdx.x * 128;
  const int kc = blockIdx.y * KCH;

  f32x4 acc[8];
#pragma unroll
  for (int ns = 0; ns < 8; ++ns)
    acc[ns] = (f32x4){0.f, 0.f, 0.f, 0.f};

  // this wave's 16 C-rows are w*16 .. w*16+15; lane lm owns row w*16+lm
  const float* arow = conn + (size_t)(a0 + w * 16 + lm) * K_TOT;

  // ---- B async stage: 32 KB contiguous from Gt + k0*128 shorts ----
  auto stageB = [&](int buf, int k0) {
    const char* gB = (const char*)(Gt + (size_t)k0 * 128);
#pragma unroll
    for (int r = 0; r < 4; ++r) {
      const void* g = gB + (size_t)(r * 512 + t) * 16;
      void* lb = (void*)((char*)&Bh[buf][0] + r * 8192 + w * 1024);  // wave-uniform
      async_ld16(g, lb);
    }
  };

  // ---- A register loads: [kk][lo/hi] fp32, non-temporal ----
  f32x4 Ar[4][2];
  auto loadA = [&](int k0) {
#pragma unroll
    for (int kk = 0; kk < 4; ++kk) {
      const float* p = arow + k0 + kk * 32 + q4 * 8;
      Ar[kk][0] = __builtin_nontemporal_load((const f32x4*)p);
      Ar[kk][1] = __builtin_nontemporal_load((const f32x4*)(p + 4));
    }
  };

  // prologue
  stageB(0, kc);
  loadA(kc);
  __syncthreads();  // drain: Bh[0] + Ar(it=0) ready

  for (int it = 0; it < NIT; ++it) {
    const int cur = it & 1;

    // convert current A to bf16 fragments (2 add + 1 perm per pair)
    bf16x8 af[4];
#pragma unroll
    for (int kk = 0; kk < 4; ++kk) {
      f32x4 lo = Ar[kk][0], hi = Ar[kk][1];
      union { bf16x8 v; uint32_t u[4]; } cvt;
      cvt.u[0] = pack_bf2(lo[0], lo[1]);
      cvt.u[1] = pack_bf2(lo[2], lo[3]);
      cvt.u[2] = pack_bf2(hi[0], hi[1]);
      cvt.u[3] = pack_bf2(hi[2], hi[3]);
      af[kk] = cvt.v;
    }

    // issue next iteration's loads BEFORE compute (overlap + barrier drain)
    if (it + 1 < NIT) {
      stageB(1 - cur, kc + (it + 1) * BK2);
      loadA(kc + (it + 1) * BK2);
    }

    // compute: 4 K-steps of 16x16x32 over Bh[cur]
#pragma unroll
    for (int kk = 0; kk < 4; ++kk) {
      const int b_rel = 2 * kk + (q4 >> 1);
      const int f0 = (q4 & 1) * 8;
#pragma unroll
      for (int ns = 0; ns < 8; ++ns) {
        int o = ns * 16 + lm;
        bf16x8 b = *(const bf16x8*)&Bh[cur][b_rel * 2048 + o * 16 + f0];
        acc[ns] = __builtin_amdgcn_mfma_f32_16x16x32_bf16(af[kk], b, acc[ns], 0, 0, 0);
      }
    }

    __syncthreads();  // drains next-iter loads (overlapped) + protects Bh swap
  }

  // epilogue: split-K combine via fp32 atomics (16-lane coalesced segments)
#pragma unroll
  for (int ns = 0; ns < 8; ++ns)
#pragma unroll
    for (int i = 0; i < 4; ++i) {
      int m = w * 16 + q4 * 4 + i;
      int n = ns * 16 + lm;
      atomicAdd(&out[(size_t)(a0 + m) * 128 + n], acc[ns][i]);
    }
}

// ---------------------------------------------------------------------------
extern "C" void kernel_launch(void* const* d_in, const int* in_sizes, int n_in,
                              void* d_out, int out_size, void* d_ws, size_t ws_size,
                              hipStream_t stream) {
  const float* node = (const float*)d_in[0];  // (2048, 128)
  const float* conn = (const float*)d_in[1];  // (2048, 2048, 16)
  const float* bond = (const float*)d_in[2];  // (2048, 16, 2)
  const float* filt = (const float*)d_in[3];  // (128, 16, 130)
  float* out = (float*)d_out;                 // (2048, 128)

  if (ws_size < (size_t)N_ATOM * 2048 * sizeof(unsigned short)) return;  // need 8 MB
  unsigned short* Gt = (unsigned short*)d_ws;  // [b][o][f] bf16, 8 MB

  k_gt  <<<dim3(16, 16), 256, 0, stream>>>(node, filt, Gt);
  k_bond<<<dim3(128),    256, 0, stream>>>(bond, filt, out);
  k_main<<<dim3(16, 16), 512, 0, stream>>>(conn, Gt, out);
}